// Round 3
// baseline (5189.962 us; speedup 1.0000x reference)
//
#include <hip/hip_runtime.h>
#include <math.h>

#define N_EL    16
#define N_NUC   4
#define N_FEATS 32
#define HIDDEN  64
#define G       8            // threads per batch element
#define TB      32           // batch elements per block
#define BLOCK   256

// triu_indices(16, 1)
__constant__ unsigned char c_I[120] = {
    0,0,0,0,0,0,0,0,0,0,0,0,0,0,0,
    1,1,1,1,1,1,1,1,1,1,1,1,1,1,
    2,2,2,2,2,2,2,2,2,2,2,2,2,
    3,3,3,3,3,3,3,3,3,3,3,3,
    4,4,4,4,4,4,4,4,4,4,4,
    5,5,5,5,5,5,5,5,5,5,
    6,6,6,6,6,6,6,6,6,
    7,7,7,7,7,7,7,7,
    8,8,8,8,8,8,8,
    9,9,9,9,9,9,
    10,10,10,10,10,
    11,11,11,11,
    12,12,12,
    13,13,
    14
};
__constant__ unsigned char c_J[120] = {
    1,2,3,4,5,6,7,8,9,10,11,12,13,14,15,
    2,3,4,5,6,7,8,9,10,11,12,13,14,15,
    3,4,5,6,7,8,9,10,11,12,13,14,15,
    4,5,6,7,8,9,10,11,12,13,14,15,
    5,6,7,8,9,10,11,12,13,14,15,
    6,7,8,9,10,11,12,13,14,15,
    7,8,9,10,11,12,13,14,15,
    8,9,10,11,12,13,14,15,
    9,10,11,12,13,14,15,
    10,11,12,13,14,15,
    11,12,13,14,15,
    12,13,14,15,
    13,14,15,
    14,15,
    15
};

// shifted softplus: softplus(x) - log(2), numerically stable
__device__ __forceinline__ float ssp(float x) {
    float a = fabsf(x);
    return fmaxf(x, 0.0f) + log1pf(__expf(-a)) - 0.69314718056f;
}

// sum over the 8 g-lanes (low 3 lane bits)
__device__ __forceinline__ float redg(float v) {
    v += __shfl_xor(v, 1);
    v += __shfl_xor(v, 2);
    v += __shfl_xor(v, 4);
    return v;
}

// NOTE (R1/R2 post-mortem): NO local arrays anywhere in this kernel.
// A 64-float acc[] was demoted to scratch (VGPR_Count=52, 5.2 ms) because
// one runtime-indexed access blocks SROA; #pragma unroll did NOT fix it.
// All accumulators are named float4s accessed via token-pasting macros.
__global__ __launch_bounds__(BLOCK, 4)
void wfnet_kernel(const float* __restrict__ rs,
                  const float* __restrict__ coords,
                  const float* __restrict__ charges,
                  const float* __restrict__ W1,
                  const float* __restrict__ b1,
                  const float* __restrict__ W2,
                  const float* __restrict__ b2,
                  const float* __restrict__ W3,
                  const float* __restrict__ b3,
                  float* __restrict__ out)
{
    __shared__ float  lds_rs[TB * N_EL * 3];   // 6 KB
    __shared__ float2 lds_ms[N_FEATS];         // {mu*s, s}, s = 1/sigma

    const int tid     = threadIdx.x;
    const int b_local = tid >> 3;              // 0..31
    const int g       = tid & 7;               // 0..7
    const int b       = blockIdx.x * TB + b_local;

    // stage this block's rs rows (coalesced)
    {
        const float* rs_blk = rs + (size_t)blockIdx.x * (TB * N_EL * 3);
        for (int k = tid; k < TB * N_EL * 3; k += BLOCK) lds_rs[k] = rs_blk[k];
    }
    // per-feature constants once per block (keeps the fp32 divide out of
    // the hot loop, full IEEE precision preserved)
    if (tid < N_FEATS) {
        const float qs = (float)tid * (1.0f / 31.0f);
        const float mu = 10.0f * qs * qs;
        const float sg = (1.0f + 10.0f * qs) * (1.0f / 7.0f);
        const float s  = 1.0f / sg;
        lds_ms[tid] = make_float2(mu * s, s);
    }
    __syncthreads();

    const float* myrs = lds_rs + b_local * (N_EL * 3);

    const float4 zero4 = make_float4(0.f, 0.f, 0.f, 0.f);
    float4 A0 = zero4, A1 = zero4, A2  = zero4, A3  = zero4,
           A4 = zero4, A5 = zero4, A6  = zero4, A7  = zero4,
           A8 = zero4, A9 = zero4, A10 = zero4, A11 = zero4,
           A12 = zero4, A13 = zero4, A14 = zero4, A15 = zero4;
    float asy = 0.0f;

    const float4* __restrict__ W1v = (const float4*)W1;
    const float4 ch = *(const float4*)charges;

#define FMA4(n) { const float4 w = r[n]; \
    A##n.x = fmaf(x, w.x, A##n.x); \
    A##n.y = fmaf(x, w.y, A##n.y); \
    A##n.z = fmaf(x, w.z, A##n.z); \
    A##n.w = fmaf(x, w.w, A##n.w); }

#define FEATS(dv, rowp) { \
    const float4* __restrict__ row = (rowp); \
    for (int f = 0; f < N_FEATS; ++f) { \
        const float2 ms = lds_ms[f]; \
        const float t = fmaf((dv), ms.y, -ms.x); \
        const float x = __expf(-(t * t)); \
        const float4* __restrict__ r = row + (f << 4); \
        FMA4(0)  FMA4(1)  FMA4(2)  FMA4(3) \
        FMA4(4)  FMA4(5)  FMA4(6)  FMA4(7) \
        FMA4(8)  FMA4(9)  FMA4(10) FMA4(11) \
        FMA4(12) FMA4(13) FMA4(14) FMA4(15) \
    } }

    // ---- electron-nucleus pairs: p = g + 8*i, i = 0..7 (wave-uniform) ----
    for (int i = 0; i < 8; ++i) {
        const int p = g + 8 * i;
        const int e = p >> 2, n = p & 3;
        const float dx = myrs[e * 3 + 0] - coords[n * 3 + 0];
        const float dy = myrs[e * 3 + 1] - coords[n * 3 + 1];
        const float dz = myrs[e * 3 + 2] - coords[n * 3 + 2];
        const float d  = sqrtf(dx * dx + dy * dy + dz * dz);
        const float Z  = (n < 2) ? ((n == 0) ? ch.x : ch.y)
                                 : ((n == 2) ? ch.z : ch.w);
        asy += (Z * d + d * d) / (1.0f + d);    // decay=sqrt(2*0.5)=1
        FEATS(d, W1v + ((size_t)p << 9));
    }
    // ---- electron-electron pairs: q = g + 8*i, i = 0..14 ----
    for (int i = 0; i < 15; ++i) {
        const int q  = g + 8 * i;
        const int ei = 3 * (int)c_I[q], ej = 3 * (int)c_J[q];
        const float dx = myrs[ei + 0] - myrs[ej + 0];
        const float dy = myrs[ei + 1] - myrs[ej + 1];
        const float dz = myrs[ei + 2] - myrs[ej + 2];
        const float d  = sqrtf(dx * dx + dy * dy + dz * dz);
        FEATS(d, W1v + ((size_t)(64 + q) << 9));
    }

    // ---- h1 = ssp(sum_g partial + b1), stored back into A components ----
    const float4* __restrict__ b1v = (const float4*)b1;
#define RED(n) { const float4 bb = b1v[n]; \
    A##n.x = ssp(redg(A##n.x) + bb.x); \
    A##n.y = ssp(redg(A##n.y) + bb.y); \
    A##n.z = ssp(redg(A##n.z) + bb.z); \
    A##n.w = ssp(redg(A##n.w) + bb.w); }
    RED(0)  RED(1)  RED(2)  RED(3)
    RED(4)  RED(5)  RED(6)  RED(7)
    RED(8)  RED(9)  RED(10) RED(11)
    RED(12) RED(13) RED(14) RED(15)
    asy = redg(asy);

    // ---- layer 2: lane g computes outputs g*8 .. g*8+7 ----
    const float4* __restrict__ W2v = (const float4*)W2;
    const float4* __restrict__ b2v = (const float4*)b2;
    const int wbi = g * 2;
    const float4 b2a = b2v[wbi], b2b = b2v[wbi + 1];
    float s0 = b2a.x, s1 = b2a.y, s2 = b2a.z, s3 = b2a.w;
    float s4 = b2b.x, s5 = b2b.y, s6 = b2b.z, s7 = b2b.w;

#define L2K(hk, k) { const float4 wa = W2v[(k) * 16 + wbi]; \
    const float4 wbv = W2v[(k) * 16 + wbi + 1]; \
    s0 = fmaf(hk, wa.x, s0);  s1 = fmaf(hk, wa.y, s1); \
    s2 = fmaf(hk, wa.z, s2);  s3 = fmaf(hk, wa.w, s3); \
    s4 = fmaf(hk, wbv.x, s4); s5 = fmaf(hk, wbv.y, s5); \
    s6 = fmaf(hk, wbv.z, s6); s7 = fmaf(hk, wbv.w, s7); }
#define L2Q(n) L2K(A##n.x, 4*(n)+0) L2K(A##n.y, 4*(n)+1) \
               L2K(A##n.z, 4*(n)+2) L2K(A##n.w, 4*(n)+3)
    L2Q(0)  L2Q(1)  L2Q(2)  L2Q(3)
    L2Q(4)  L2Q(5)  L2Q(6)  L2Q(7)
    L2Q(8)  L2Q(9)  L2Q(10) L2Q(11)
    L2Q(12) L2Q(13) L2Q(14) L2Q(15)

    // ---- layer 3 partial dot over this lane's 8 outputs ----
    const float4* __restrict__ W3v = (const float4*)W3;
    const float4 w3a = W3v[wbi], w3b = W3v[wbi + 1];
    float part = ssp(s0) * w3a.x + ssp(s1) * w3a.y
               + ssp(s2) * w3a.z + ssp(s3) * w3a.w
               + ssp(s4) * w3b.x + ssp(s5) * w3b.y
               + ssp(s6) * w3b.z + ssp(s7) * w3b.w;
    part = redg(part);

    if (g == 0) {
        const float ys = part + b3[0];
        out[b] = __expf(ys) * __expf(-asy);
    }
}

extern "C" void kernel_launch(void* const* d_in, const int* in_sizes, int n_in,
                              void* d_out, int out_size, void* d_ws, size_t ws_size,
                              hipStream_t stream) {
    const float* rs      = (const float*)d_in[0];
    const float* coords  = (const float*)d_in[1];
    const float* charges = (const float*)d_in[2];
    const float* W1      = (const float*)d_in[3];
    const float* b1      = (const float*)d_in[4];
    const float* W2      = (const float*)d_in[5];
    const float* b2      = (const float*)d_in[6];
    const float* W3      = (const float*)d_in[7];
    const float* b3      = (const float*)d_in[8];
    float* out = (float*)d_out;

    const int batch = in_sizes[0] / (N_EL * 3);   // 32768
    const int grid  = batch / TB;                 // 1024 blocks

    wfnet_kernel<<<grid, BLOCK, 0, stream>>>(rs, coords, charges,
                                             W1, b1, W2, b2, W3, b3, out);
}

// Round 4
// 5187.100 us; speedup vs baseline: 1.0006x; 1.0006x over previous
//
#include <hip/hip_runtime.h>
#include <math.h>

#define N_EL    16
#define N_NUC   4
#define N_FEATS 32
#define HIDDEN  64
#define G       8            // threads per batch element
#define TB      32           // batch elements per block
#define BLOCK   256

// triu_indices(16, 1)
__constant__ unsigned char c_I[120] = {
    0,0,0,0,0,0,0,0,0,0,0,0,0,0,0,
    1,1,1,1,1,1,1,1,1,1,1,1,1,1,
    2,2,2,2,2,2,2,2,2,2,2,2,2,
    3,3,3,3,3,3,3,3,3,3,3,3,
    4,4,4,4,4,4,4,4,4,4,4,
    5,5,5,5,5,5,5,5,5,5,
    6,6,6,6,6,6,6,6,6,
    7,7,7,7,7,7,7,7,
    8,8,8,8,8,8,8,
    9,9,9,9,9,9,
    10,10,10,10,10,
    11,11,11,11,
    12,12,12,
    13,13,
    14
};
__constant__ unsigned char c_J[120] = {
    1,2,3,4,5,6,7,8,9,10,11,12,13,14,15,
    2,3,4,5,6,7,8,9,10,11,12,13,14,15,
    3,4,5,6,7,8,9,10,11,12,13,14,15,
    4,5,6,7,8,9,10,11,12,13,14,15,
    5,6,7,8,9,10,11,12,13,14,15,
    6,7,8,9,10,11,12,13,14,15,
    7,8,9,10,11,12,13,14,15,
    8,9,10,11,12,13,14,15,
    9,10,11,12,13,14,15,
    10,11,12,13,14,15,
    11,12,13,14,15,
    12,13,14,15,
    13,14,15,
    14,15,
    15
};

// shifted softplus: softplus(x) - log(2), numerically stable
__device__ __forceinline__ float ssp(float x) {
    float a = fabsf(x);
    return fmaxf(x, 0.0f) + log1pf(__expf(-a)) - 0.69314718056f;
}

// sum over the 8 g-lanes (low 3 lane bits)
__device__ __forceinline__ float redg(float v) {
    v += __shfl_xor(v, 1);
    v += __shfl_xor(v, 2);
    v += __shfl_xor(v, 4);
    return v;
}

// R1/R2 post-mortem: NO local arrays (SROA can't split a runtime-indexed
// alloca; acc[] went to scratch). R3 post-mortem: named values STILL
// spilled because the allocator squeezed to the 64-VGPR occupancy step
// (8 waves/SIMD) even though occupancy is grid-limited at 4 waves/SIMD.
// amdgpu_waves_per_eu(4,4) pins the budget at 128 VGPRs -> no spill.
__global__ __launch_bounds__(BLOCK)
__attribute__((amdgpu_waves_per_eu(4, 4)))
void wfnet_kernel(const float* __restrict__ rs,
                  const float* __restrict__ coords,
                  const float* __restrict__ charges,
                  const float* __restrict__ W1,
                  const float* __restrict__ b1,
                  const float* __restrict__ W2,
                  const float* __restrict__ b2,
                  const float* __restrict__ W3,
                  const float* __restrict__ b3,
                  float* __restrict__ out)
{
    __shared__ float  lds_rs[TB * N_EL * 3];   // 6 KB
    __shared__ float2 lds_ms[N_FEATS];         // {mu*s, s}, s = 1/sigma

    const int tid     = threadIdx.x;
    const int b_local = tid >> 3;              // 0..31
    const int g       = tid & 7;               // 0..7
    const int b       = blockIdx.x * TB + b_local;

    // stage this block's rs rows (coalesced)
    {
        const float* rs_blk = rs + (size_t)blockIdx.x * (TB * N_EL * 3);
        for (int k = tid; k < TB * N_EL * 3; k += BLOCK) lds_rs[k] = rs_blk[k];
    }
    // per-feature constants once per block (keeps the fp32 divide out of
    // the hot loop, full IEEE precision preserved)
    if (tid < N_FEATS) {
        const float qs = (float)tid * (1.0f / 31.0f);
        const float mu = 10.0f * qs * qs;
        const float sg = (1.0f + 10.0f * qs) * (1.0f / 7.0f);
        const float s  = 1.0f / sg;
        lds_ms[tid] = make_float2(mu * s, s);
    }
    __syncthreads();

    const float* myrs = lds_rs + b_local * (N_EL * 3);

    const float4 zero4 = make_float4(0.f, 0.f, 0.f, 0.f);
    float4 A0 = zero4, A1 = zero4, A2  = zero4, A3  = zero4,
           A4 = zero4, A5 = zero4, A6  = zero4, A7  = zero4,
           A8 = zero4, A9 = zero4, A10 = zero4, A11 = zero4,
           A12 = zero4, A13 = zero4, A14 = zero4, A15 = zero4;
    float asy = 0.0f;

    const float4* __restrict__ W1v = (const float4*)W1;
    const float4 ch = *(const float4*)charges;

#define FMA4(n) { const float4 w = r[n]; \
    A##n.x = fmaf(x, w.x, A##n.x); \
    A##n.y = fmaf(x, w.y, A##n.y); \
    A##n.z = fmaf(x, w.z, A##n.z); \
    A##n.w = fmaf(x, w.w, A##n.w); }

#define FEATS(dv, rowp) { \
    const float4* __restrict__ row = (rowp); \
    for (int f = 0; f < N_FEATS; ++f) { \
        const float2 ms = lds_ms[f]; \
        const float t = fmaf((dv), ms.y, -ms.x); \
        const float x = __expf(-(t * t)); \
        const float4* __restrict__ r = row + (f << 4); \
        FMA4(0)  FMA4(1)  FMA4(2)  FMA4(3) \
        FMA4(4)  FMA4(5)  FMA4(6)  FMA4(7) \
        FMA4(8)  FMA4(9)  FMA4(10) FMA4(11) \
        FMA4(12) FMA4(13) FMA4(14) FMA4(15) \
    } }

    // ---- electron-nucleus pairs: p = g + 8*i, i = 0..7 (wave-uniform) ----
    for (int i = 0; i < 8; ++i) {
        const int p = g + 8 * i;
        const int e = p >> 2, n = p & 3;
        const float dx = myrs[e * 3 + 0] - coords[n * 3 + 0];
        const float dy = myrs[e * 3 + 1] - coords[n * 3 + 1];
        const float dz = myrs[e * 3 + 2] - coords[n * 3 + 2];
        const float d  = sqrtf(dx * dx + dy * dy + dz * dz);
        const float Z  = (n < 2) ? ((n == 0) ? ch.x : ch.y)
                                 : ((n == 2) ? ch.z : ch.w);
        asy += (Z * d + d * d) / (1.0f + d);    // decay=sqrt(2*0.5)=1
        FEATS(d, W1v + ((size_t)p << 9));
    }
    // ---- electron-electron pairs: q = g + 8*i, i = 0..14 ----
    for (int i = 0; i < 15; ++i) {
        const int q  = g + 8 * i;
        const int ei = 3 * (int)c_I[q], ej = 3 * (int)c_J[q];
        const float dx = myrs[ei + 0] - myrs[ej + 0];
        const float dy = myrs[ei + 1] - myrs[ej + 1];
        const float dz = myrs[ei + 2] - myrs[ej + 2];
        const float d  = sqrtf(dx * dx + dy * dy + dz * dz);
        FEATS(d, W1v + ((size_t)(64 + q) << 9));
    }

    // ---- h1 = ssp(sum_g partial + b1), stored back into A components ----
    const float4* __restrict__ b1v = (const float4*)b1;
#define RED(n) { const float4 bb = b1v[n]; \
    A##n.x = ssp(redg(A##n.x) + bb.x); \
    A##n.y = ssp(redg(A##n.y) + bb.y); \
    A##n.z = ssp(redg(A##n.z) + bb.z); \
    A##n.w = ssp(redg(A##n.w) + bb.w); }
    RED(0)  RED(1)  RED(2)  RED(3)
    RED(4)  RED(5)  RED(6)  RED(7)
    RED(8)  RED(9)  RED(10) RED(11)
    RED(12) RED(13) RED(14) RED(15)
    asy = redg(asy);

    // ---- layer 2: lane g computes outputs g*8 .. g*8+7 ----
    const float4* __restrict__ W2v = (const float4*)W2;
    const float4* __restrict__ b2v = (const float4*)b2;
    const int wbi = g * 2;
    const float4 b2a = b2v[wbi], b2b = b2v[wbi + 1];
    float s0 = b2a.x, s1 = b2a.y, s2 = b2a.z, s3 = b2a.w;
    float s4 = b2b.x, s5 = b2b.y, s6 = b2b.z, s7 = b2b.w;

#define L2K(hk, k) { const float4 wa = W2v[(k) * 16 + wbi]; \
    const float4 wbv = W2v[(k) * 16 + wbi + 1]; \
    s0 = fmaf(hk, wa.x, s0);  s1 = fmaf(hk, wa.y, s1); \
    s2 = fmaf(hk, wa.z, s2);  s3 = fmaf(hk, wa.w, s3); \
    s4 = fmaf(hk, wbv.x, s4); s5 = fmaf(hk, wbv.y, s5); \
    s6 = fmaf(hk, wbv.z, s6); s7 = fmaf(hk, wbv.w, s7); }
#define L2Q(n) L2K(A##n.x, 4*(n)+0) L2K(A##n.y, 4*(n)+1) \
               L2K(A##n.z, 4*(n)+2) L2K(A##n.w, 4*(n)+3)
    L2Q(0)  L2Q(1)  L2Q(2)  L2Q(3)
    L2Q(4)  L2Q(5)  L2Q(6)  L2Q(7)
    L2Q(8)  L2Q(9)  L2Q(10) L2Q(11)
    L2Q(12) L2Q(13) L2Q(14) L2Q(15)

    // ---- layer 3 partial dot over this lane's 8 outputs ----
    const float4* __restrict__ W3v = (const float4*)W3;
    const float4 w3a = W3v[wbi], w3b = W3v[wbi + 1];
    float part = ssp(s0) * w3a.x + ssp(s1) * w3a.y
               + ssp(s2) * w3a.z + ssp(s3) * w3a.w
               + ssp(s4) * w3b.x + ssp(s5) * w3b.y
               + ssp(s6) * w3b.z + ssp(s7) * w3b.w;
    part = redg(part);

    if (g == 0) {
        const float ys = part + b3[0];
        out[b] = __expf(ys) * __expf(-asy);
    }
}

extern "C" void kernel_launch(void* const* d_in, const int* in_sizes, int n_in,
                              void* d_out, int out_size, void* d_ws, size_t ws_size,
                              hipStream_t stream) {
    const float* rs      = (const float*)d_in[0];
    const float* coords  = (const float*)d_in[1];
    const float* charges = (const float*)d_in[2];
    const float* W1      = (const float*)d_in[3];
    const float* b1      = (const float*)d_in[4];
    const float* W2      = (const float*)d_in[5];
    const float* b2      = (const float*)d_in[6];
    const float* W3      = (const float*)d_in[7];
    const float* b3      = (const float*)d_in[8];
    float* out = (float*)d_out;

    const int batch = in_sizes[0] / (N_EL * 3);   // 32768
    const int grid  = batch / TB;                 // 1024 blocks

    wfnet_kernel<<<grid, BLOCK, 0, stream>>>(rs, coords, charges,
                                             W1, b1, W2, b2, W3, b3, out);
}